// Round 7
// baseline (44.595 us; speedup 1.0000x reference)
//
#include <hip/hip_runtime.h>
#include <math.h>

#define NB 4
#define WDIM 128
#define KDIM 256
#define EDIM 256

__device__ __forceinline__ float dot4(float4 a, float4 b) {
    return a.x * b.x + a.y * b.y + a.z * b.z + a.w * b.w;
}

// ---------------- k_ut7: dual GEMM u,t + t-transpose ----------------
// grid 512: blk = b*128 + kt*4 + eq. Block = 8 k x 64 e.
// u_ws[b][k][e] = sum_w v*W1;  tT_ws[b][e][k] = sum_w v*W2 + lin_b[e]
__global__ __launch_bounds__(256) void k_ut7(const float* __restrict__ x,
                                             const float* __restrict__ lin_w,
                                             const float* __restrict__ lin_b,
                                             float* __restrict__ u_ws,
                                             float* __restrict__ tT_ws) {
    __shared__ float vrow[8 * WDIM];   // [k 8][w 128]
    __shared__ float t_lds[64][9];     // [e 64][k 8] padded
    const int blk = blockIdx.x;
    const int b  = blk >> 7;
    const int kt = (blk >> 2) & 31;
    const int eq = blk & 3;
    const int k0 = kt * 8;
    const int tid = threadIdx.x;
    const int el  = tid & 63;
    const int e   = eq * 64 + el;
    const int ks  = tid >> 6;

    if (tid < WDIM) {
        const float* xp = x + ((size_t)b * WDIM + tid) * KDIM + k0;
        float4 v0 = *(const float4*)xp;
        float4 v1 = *(const float4*)(xp + 4);
        vrow[0 * WDIM + tid] = v0.x; vrow[1 * WDIM + tid] = v0.y;
        vrow[2 * WDIM + tid] = v0.z; vrow[3 * WDIM + tid] = v0.w;
        vrow[4 * WDIM + tid] = v1.x; vrow[5 * WDIM + tid] = v1.y;
        vrow[6 * WDIM + tid] = v1.z; vrow[7 * WDIM + tid] = v1.w;
    }
    __syncthreads();

    const float4* wr = (const float4*)(lin_w + (size_t)e * 2 * WDIM);
    float u0 = 0.f, u1 = 0.f, t0 = 0.f, t1 = 0.f;
#pragma unroll 8
    for (int q = 0; q < 32; ++q) {
        float4 w1 = wr[q];
        float4 w2 = wr[32 + q];
        float4 va = *(const float4*)&vrow[(ks * 2 + 0) * WDIM + q * 4];
        float4 vb = *(const float4*)&vrow[(ks * 2 + 1) * WDIM + q * 4];
        u0 += dot4(w1, va); u1 += dot4(w1, vb);
        t0 += dot4(w2, va); t1 += dot4(w2, vb);
    }
    const float lb = lin_b[e];
    const int k = k0 + ks * 2;
    const size_t o0 = ((size_t)b * KDIM + k) * EDIM + e;
    u_ws[o0] = u0;  u_ws[o0 + EDIM] = u1;

    t_lds[el][ks * 2 + 0] = t0 + lb;
    t_lds[el][ks * 2 + 1] = t1 + lb;
    __syncthreads();

    // write tT: thread -> (e_w = tid>>2, pair of k's)
    const int e_w = tid >> 2;
    const int c2  = (tid & 3) * 2;
    float2 tv = make_float2(t_lds[e_w][c2], t_lds[e_w][c2 + 1]);
    *(float2*)(tT_ws + ((size_t)b * EDIM + eq * 64 + e_w) * KDIM + k0 + c2) = tv;
}

// ---------------- k_e7: partial z[eh][b][i][j] ----------------
// z_eh[i,j] = sum_{e in quarter} 0.4a|u_ie + tT_ej| + 0.6a*tT_ej
// grid 1024: blk = b*256 + it*4 + eh. Block = 4 i (one per wave) x 256 j x 64 e.
// Lane owns j = lane*4..+4. ZERO LDS, no shfl, no barriers.
__global__ __launch_bounds__(256) void k_e7(const float* __restrict__ a_vec,
                                            const float* __restrict__ u_ws,
                                            const float* __restrict__ tT_ws,
                                            float* __restrict__ z_ws) {
    const int blk = blockIdx.x;
    const int b  = blk >> 8;
    const int it = (blk >> 2) & 63;
    const int eh = blk & 3;
    const int wv   = threadIdx.x >> 6;
    const int lane = threadIdx.x & 63;
    const int i  = it * 4 + wv;
    const int e0 = eh * 64;

    const float* urow  = u_ws + ((size_t)b * KDIM + i) * EDIM + e0;
    const float* arow  = a_vec + e0;
    const float* tbase = tT_ws + ((size_t)b * EDIM + e0) * KDIM + lane * 4;

    float4 acc = make_float4(0.f, 0.f, 0.f, 0.f);
    float4 rt  = make_float4(0.f, 0.f, 0.f, 0.f);

#pragma unroll 4
    for (int e4 = 0; e4 < 16; ++e4) {
        float4 uv = *(const float4*)(urow + e4 * 4);   // wave-uniform broadcast
        float4 av = *(const float4*)(arow + e4 * 4);
        float uc[4] = {uv.x, uv.y, uv.z, uv.w};
        float ac[4] = {av.x, av.y, av.z, av.w};
#pragma unroll
        for (int r = 0; r < 4; ++r) {
            float4 t4 = *(const float4*)(tbase + (size_t)(e4 * 4 + r) * KDIM);
            const float c = 0.4f * ac[r];
            const float d = 0.6f * ac[r];
            acc.x += c * fabsf(uc[r] + t4.x);  rt.x += d * t4.x;
            acc.y += c * fabsf(uc[r] + t4.y);  rt.y += d * t4.y;
            acc.z += c * fabsf(uc[r] + t4.z);  rt.z += d * t4.z;
            acc.w += c * fabsf(uc[r] + t4.w);  rt.w += d * t4.w;
        }
    }
    float4 z;
    z.x = acc.x + rt.x; z.y = acc.y + rt.y;
    z.z = acc.z + rt.z; z.w = acc.w + rt.w;
    *(float4*)(z_ws + (size_t)eh * (NB * KDIM * KDIM)
                    + ((size_t)b * KDIM + i) * KDIM + lane * 4) = z;
}

// ---------------- k_sh7: combine + ru + bias + softmax + h ----------------
// grid 1024: blk = b*256 + it*4 + wq. Block = 4 i x 32 w.
__global__ __launch_bounds__(256) void k_sh7(const float* __restrict__ x,
                                             const float* __restrict__ a_vec,
                                             const float* __restrict__ bias,
                                             const float* __restrict__ u_ws,
                                             const float* __restrict__ z_ws,
                                             float* __restrict__ out) {
    __shared__ float attn_lds[4][260];
    const int blk = blockIdx.x;
    const int b  = blk >> 8;
    const int it = (blk >> 2) & 63;
    const int wq = blk & 3;
    const int i0 = it * 4;
    const int w0 = wq * 32;
    const int tid  = threadIdx.x;
    const int wv   = tid >> 6;
    const int lane = tid & 63;
    const int i = i0 + wv;

    // combine 4 e-quarter partials + ru + bias, then softmax (wave-parallel)
    {
        const size_t plane = (size_t)NB * KDIM * KDIM;
        const size_t roff  = ((size_t)b * KDIM + i) * KDIM + lane * 4;
        float4 z0 = *(const float4*)(z_ws + roff);
        float4 z1 = *(const float4*)(z_ws + plane + roff);
        float4 z2 = *(const float4*)(z_ws + 2 * plane + roff);
        float4 z3 = *(const float4*)(z_ws + 3 * plane + roff);

        float4 uv = *(const float4*)(u_ws + ((size_t)b * KDIM + i) * EDIM + lane * 4);
        float4 av = *(const float4*)(a_vec + lane * 4);
        float ru = 0.6f * dot4(av, uv);
#pragma unroll
        for (int o = 1; o < 64; o <<= 1) ru += __shfl_xor(ru, o, 64);

        float4 bv = *(const float4*)(bias + (size_t)i * KDIM + lane * 4);
        float4 ev;
        ev.x = z0.x + z1.x + z2.x + z3.x + ru + bv.x;
        ev.y = z0.y + z1.y + z2.y + z3.y + ru + bv.y;
        ev.z = z0.z + z1.z + z2.z + z3.z + ru + bv.z;
        ev.w = z0.w + z1.w + z2.w + z3.w + ru + bv.w;

        float m = fmaxf(fmaxf(ev.x, ev.y), fmaxf(ev.z, ev.w));
#pragma unroll
        for (int o = 1; o < 64; o <<= 1) m = fmaxf(m, __shfl_xor(m, o, 64));
        float4 p;
        p.x = __expf(ev.x - m); p.y = __expf(ev.y - m);
        p.z = __expf(ev.z - m); p.w = __expf(ev.w - m);
        float ssum = p.x + p.y + p.z + p.w;
#pragma unroll
        for (int o = 1; o < 64; o <<= 1) ssum += __shfl_xor(ssum, o, 64);
        const float inv = 1.0f / ssum;
        p.x *= inv; p.y *= inv; p.z *= inv; p.w *= inv;
        *(float4*)&attn_lds[wv][lane * 4] = p;
    }
    __syncthreads();

    // h-phase: wave wv -> w-oct; lane: s = lane&7 (j-slices), ww = lane>>3
    const int s  = lane & 7;
    const int ww = lane >> 3;
    const int w  = w0 + wv * 8 + ww;
    const float* xr = x + ((size_t)b * WDIM + w) * KDIM;
    float acc[4] = {0.f, 0.f, 0.f, 0.f};
#pragma unroll
    for (int q = 0; q < 8; ++q) {
        float4 x4 = *(const float4*)(xr + q * 32 + s * 4);
#pragma unroll
        for (int ii = 0; ii < 4; ++ii) {
            float4 at = *(const float4*)&attn_lds[ii][q * 32 + s * 4];
            acc[ii] += dot4(at, x4);
        }
    }
#pragma unroll
    for (int ii = 0; ii < 4; ++ii) {
        acc[ii] += __shfl_xor(acc[ii], 1, 64);
        acc[ii] += __shfl_xor(acc[ii], 2, 64);
        acc[ii] += __shfl_xor(acc[ii], 4, 64);
    }
    if (s == 0) {
        float4 o;
        o.x = 1.f / (1.f + __expf(-acc[0]));
        o.y = 1.f / (1.f + __expf(-acc[1]));
        o.z = 1.f / (1.f + __expf(-acc[2]));
        o.w = 1.f / (1.f + __expf(-acc[3]));
        *(float4*)(out + ((size_t)b * WDIM + w) * KDIM + i0) = o;
    }
}

extern "C" void kernel_launch(void* const* d_in, const int* in_sizes, int n_in,
                              void* d_out, int out_size, void* d_ws, size_t ws_size,
                              hipStream_t stream) {
    (void)in_sizes; (void)n_in; (void)out_size; (void)ws_size;
    const float* x     = (const float*)d_in[0];
    const float* lin_w = (const float*)d_in[1];
    const float* lin_b = (const float*)d_in[2];
    const float* a_vec = (const float*)d_in[3];
    const float* bias  = (const float*)d_in[4];
    float* out = (float*)d_out;

    float* u_ws  = (float*)d_ws;                        // 262144 f
    float* tT_ws = u_ws + (size_t)NB * KDIM * EDIM;     // 262144 f
    float* z_ws  = tT_ws + (size_t)NB * KDIM * EDIM;    // 4*262144 f

    k_ut7<<<512, 256, 0, stream>>>(x, lin_w, lin_b, u_ws, tT_ws);
    k_e7<<<1024, 256, 0, stream>>>(a_vec, u_ws, tT_ws, z_ws);
    k_sh7<<<1024, 256, 0, stream>>>(x, a_vec, bias, u_ws, z_ws, out);
}

// Round 8
// 39.159 us; speedup vs baseline: 1.1388x; 1.1388x over previous
//
#include <hip/hip_runtime.h>
#include <math.h>

#define NB 4
#define WDIM 128
#define KDIM 256
#define EDIM 256

__device__ __forceinline__ float dot4(float4 a, float4 b) {
    return a.x * b.x + a.y * b.y + a.z * b.z + a.w * b.w;
}

// ---------------- k_ut8: dual GEMM u,t + t-transpose (round-7 structure) ----------------
// grid 512: blk = b*128 + kt*4 + eq. Block = 8 k x 64 e.
// u_ws[b][k][e] = sum_w v*W1;  tT_ws[b][e][k] = sum_w v*W2 + lin_b[e]
__global__ __launch_bounds__(256) void k_ut8(const float* __restrict__ x,
                                             const float* __restrict__ lin_w,
                                             const float* __restrict__ lin_b,
                                             float* __restrict__ u_ws,
                                             float* __restrict__ tT_ws) {
    __shared__ float vrow[8 * WDIM];   // [k 8][w 128]
    __shared__ float t_lds[64][9];     // [e 64][k 8] padded
    const int blk = blockIdx.x;
    const int b  = blk >> 7;
    const int kt = (blk >> 2) & 31;
    const int eq = blk & 3;
    const int k0 = kt * 8;
    const int tid = threadIdx.x;
    const int el  = tid & 63;
    const int e   = eq * 64 + el;
    const int ks  = tid >> 6;

    if (tid < WDIM) {
        const float* xp = x + ((size_t)b * WDIM + tid) * KDIM + k0;
        float4 v0 = *(const float4*)xp;
        float4 v1 = *(const float4*)(xp + 4);
        vrow[0 * WDIM + tid] = v0.x; vrow[1 * WDIM + tid] = v0.y;
        vrow[2 * WDIM + tid] = v0.z; vrow[3 * WDIM + tid] = v0.w;
        vrow[4 * WDIM + tid] = v1.x; vrow[5 * WDIM + tid] = v1.y;
        vrow[6 * WDIM + tid] = v1.z; vrow[7 * WDIM + tid] = v1.w;
    }
    __syncthreads();

    const float4* wr = (const float4*)(lin_w + (size_t)e * 2 * WDIM);
    float u0 = 0.f, u1 = 0.f, t0 = 0.f, t1 = 0.f;
#pragma unroll 8
    for (int q = 0; q < 32; ++q) {
        float4 w1 = wr[q];
        float4 w2 = wr[32 + q];
        float4 va = *(const float4*)&vrow[(ks * 2 + 0) * WDIM + q * 4];
        float4 vb = *(const float4*)&vrow[(ks * 2 + 1) * WDIM + q * 4];
        u0 += dot4(w1, va); u1 += dot4(w1, vb);
        t0 += dot4(w2, va); t1 += dot4(w2, vb);
    }
    const float lb = lin_b[e];
    const int k = k0 + ks * 2;
    const size_t o0 = ((size_t)b * KDIM + k) * EDIM + e;
    u_ws[o0] = u0;  u_ws[o0 + EDIM] = u1;

    t_lds[el][ks * 2 + 0] = t0 + lb;
    t_lds[el][ks * 2 + 1] = t1 + lb;
    __syncthreads();

    const int e_w = tid >> 2;
    const int c2  = (tid & 3) * 2;
    float2 tv = make_float2(t_lds[e_w][c2], t_lds[e_w][c2 + 1]);
    *(float2*)(tT_ws + ((size_t)b * EDIM + eq * 64 + e_w) * KDIM + k0 + c2) = tv;
}

// ---------------- k_fused: e + softmax + h in one kernel ----------------
// grid 256: blk = b*64 + it. Block = 1024 threads = 16 waves, owns 4 i-rows.
// Phase 1: wave (i = i0 + wv>>2, eq = wv&3) accumulates z over its 64-e quarter,
//          lane owns 4 contiguous j's (coalesced tT rows). z -> LDS.
// Phase 2: waves 0-3 combine 4 planes + ru + bias, softmax -> attn LDS.
// Phase 3: 16 waves x 8 w's: h = sigmoid(attn @ v), float4 transposed store.
__global__ __launch_bounds__(1024, 1) void k_fused(const float* __restrict__ x,
                                                   const float* __restrict__ a_vec,
                                                   const float* __restrict__ bias,
                                                   const float* __restrict__ u_ws,
                                                   const float* __restrict__ tT_ws,
                                                   float* __restrict__ out) {
    __shared__ float z_lds[16][256];     // 16 KB partial planes
    __shared__ float ru_lds[16];
    __shared__ float attn_lds[4][260];
    const int blk = blockIdx.x;
    const int b  = blk >> 6;
    const int it = blk & 63;
    const int i0 = it * 4;
    const int tid  = threadIdx.x;
    const int wv   = tid >> 6;
    const int lane = tid & 63;

    // ---- phase 1 ----
    {
        const int i  = i0 + (wv >> 2);
        const int eq = wv & 3;
        const int e0 = eq * 64;
        const float* urow  = u_ws + ((size_t)b * KDIM + i) * EDIM + e0;
        const float* arow  = a_vec + e0;
        const float* tbase = tT_ws + ((size_t)b * EDIM + e0) * KDIM + lane * 4;

        float4 acc = make_float4(0.f, 0.f, 0.f, 0.f);
        float4 rt  = make_float4(0.f, 0.f, 0.f, 0.f);
        float ru = 0.f;
#pragma unroll 4
        for (int e4 = 0; e4 < 16; ++e4) {
            float4 uv = *(const float4*)(urow + e4 * 4);   // wave-uniform
            float4 av = *(const float4*)(arow + e4 * 4);
            float uc[4] = {uv.x, uv.y, uv.z, uv.w};
            float ac[4] = {av.x, av.y, av.z, av.w};
#pragma unroll
            for (int r = 0; r < 4; ++r) {
                float4 t4 = *(const float4*)(tbase + (size_t)(e4 * 4 + r) * KDIM);
                const float c = 0.4f * ac[r];
                const float d = 0.6f * ac[r];
                acc.x += c * fabsf(uc[r] + t4.x);  rt.x += d * t4.x;
                acc.y += c * fabsf(uc[r] + t4.y);  rt.y += d * t4.y;
                acc.z += c * fabsf(uc[r] + t4.z);  rt.z += d * t4.z;
                acc.w += c * fabsf(uc[r] + t4.w);  rt.w += d * t4.w;
                ru += d * uc[r];
            }
        }
        float4 z;
        z.x = acc.x + rt.x; z.y = acc.y + rt.y;
        z.z = acc.z + rt.z; z.w = acc.w + rt.w;
        *(float4*)&z_lds[wv][lane * 4] = z;
        if (lane == 0) ru_lds[wv] = ru;
    }
    __syncthreads();

    // ---- phase 2: combine + softmax (waves 0-3) ----
    if (wv < 4) {
        float4 z0 = *(const float4*)&z_lds[wv * 4 + 0][lane * 4];
        float4 z1 = *(const float4*)&z_lds[wv * 4 + 1][lane * 4];
        float4 z2 = *(const float4*)&z_lds[wv * 4 + 2][lane * 4];
        float4 z3 = *(const float4*)&z_lds[wv * 4 + 3][lane * 4];
        const float ru = ru_lds[wv * 4] + ru_lds[wv * 4 + 1]
                       + ru_lds[wv * 4 + 2] + ru_lds[wv * 4 + 3];
        float4 bv = *(const float4*)(bias + (size_t)(i0 + wv) * KDIM + lane * 4);
        float4 ev;
        ev.x = z0.x + z1.x + z2.x + z3.x + ru + bv.x;
        ev.y = z0.y + z1.y + z2.y + z3.y + ru + bv.y;
        ev.z = z0.z + z1.z + z2.z + z3.z + ru + bv.z;
        ev.w = z0.w + z1.w + z2.w + z3.w + ru + bv.w;

        float m = fmaxf(fmaxf(ev.x, ev.y), fmaxf(ev.z, ev.w));
#pragma unroll
        for (int o = 1; o < 64; o <<= 1) m = fmaxf(m, __shfl_xor(m, o, 64));
        float4 p;
        p.x = __expf(ev.x - m); p.y = __expf(ev.y - m);
        p.z = __expf(ev.z - m); p.w = __expf(ev.w - m);
        float ssum = p.x + p.y + p.z + p.w;
#pragma unroll
        for (int o = 1; o < 64; o <<= 1) ssum += __shfl_xor(ssum, o, 64);
        const float inv = 1.0f / ssum;
        p.x *= inv; p.y *= inv; p.z *= inv; p.w *= inv;
        *(float4*)&attn_lds[wv][lane * 4] = p;
    }
    __syncthreads();

    // ---- phase 3: h = sigmoid(attn @ v) ----
    const int s  = lane & 7;
    const int ww = lane >> 3;
    const int w  = wv * 8 + ww;
    const float* xr = x + ((size_t)b * WDIM + w) * KDIM;
    float acc[4] = {0.f, 0.f, 0.f, 0.f};
#pragma unroll
    for (int q = 0; q < 8; ++q) {
        float4 x4 = *(const float4*)(xr + q * 32 + s * 4);
#pragma unroll
        for (int ii = 0; ii < 4; ++ii) {
            float4 at = *(const float4*)&attn_lds[ii][q * 32 + s * 4];
            acc[ii] += dot4(at, x4);
        }
    }
#pragma unroll
    for (int ii = 0; ii < 4; ++ii) {
        acc[ii] += __shfl_xor(acc[ii], 1, 64);
        acc[ii] += __shfl_xor(acc[ii], 2, 64);
        acc[ii] += __shfl_xor(acc[ii], 4, 64);
    }
    if (s == 0) {
        float4 o;
        o.x = 1.f / (1.f + __expf(-acc[0]));
        o.y = 1.f / (1.f + __expf(-acc[1]));
        o.z = 1.f / (1.f + __expf(-acc[2]));
        o.w = 1.f / (1.f + __expf(-acc[3]));
        *(float4*)(out + ((size_t)b * WDIM + w) * KDIM + i0) = o;
    }
}

extern "C" void kernel_launch(void* const* d_in, const int* in_sizes, int n_in,
                              void* d_out, int out_size, void* d_ws, size_t ws_size,
                              hipStream_t stream) {
    (void)in_sizes; (void)n_in; (void)out_size; (void)ws_size;
    const float* x     = (const float*)d_in[0];
    const float* lin_w = (const float*)d_in[1];
    const float* lin_b = (const float*)d_in[2];
    const float* a_vec = (const float*)d_in[3];
    const float* bias  = (const float*)d_in[4];
    float* out = (float*)d_out;

    float* u_ws  = (float*)d_ws;                        // 262144 f
    float* tT_ws = u_ws + (size_t)NB * KDIM * EDIM;     // 262144 f

    k_ut8<<<512, 256, 0, stream>>>(x, lin_w, lin_b, u_ws, tT_ws);
    k_fused<<<256, 1024, 0, stream>>>(x, a_vec, bias, u_ws, tT_ws, out);
}